// Round 4
// baseline (541.123 us; speedup 1.0000x reference)
//
#include <hip/hip_runtime.h>

// MessagePassing: out[dst[e], :] += w[e] * x[src[e], :]
// N=100000, E=1000000, F=64, fp32.
// Strategy: bin edges by 128-node dst bucket (LDS-privatized hist -> tiny
// scan -> chunked scatter of packed records), then one block per bucket
// accumulates into a 33 KB LDS tile and writes out coalesced.
// No atomics on out, no per-node CSR.

#define FDIM 64
#define BSHIFT 7
#define BNODES 128          // nodes per bucket
#define STRIDE 65           // LDS row stride (floats) to break bank conflicts
#define BMAX 1024           // max buckets supported (N <= 131072)
#define SC_EPT 16           // scatter: edges per thread
#define SC_EPB (256 * SC_EPT)
#define H_EPT 8             // hist: edges per thread
#define H_EPB (256 * H_EPT)

// ---------------- fallback: round-1 atomic kernel ----------
__global__ void __launch_bounds__(256)
scatter_edges_kernel(const float* __restrict__ x,
                     const float* __restrict__ w,
                     const int* __restrict__ src,
                     const int* __restrict__ dst,
                     float* __restrict__ out,
                     int E) {
    int gid = blockIdx.x * blockDim.x + threadIdx.x;
    int e = gid >> 4;
    int q = gid & 15;
    if (e >= E) return;
    int s = src[e];
    int d = dst[e];
    float we = w[e];
    const float4* xrow = reinterpret_cast<const float4*>(x + (size_t)s * FDIM);
    float4 v = xrow[q];
    float* o = out + (size_t)d * FDIM + q * 4;
    atomicAdd(o + 0, we * v.x);
    atomicAdd(o + 1, we * v.y);
    atomicAdd(o + 2, we * v.z);
    atomicAdd(o + 3, we * v.w);
}

// ---------------- bucket path ----------------
__global__ void __launch_bounds__(256)
bucket_hist(const int* __restrict__ dst, int* __restrict__ bcnt, int E, int B) {
    __shared__ int h[BMAX];
    int t = threadIdx.x;
    for (int i = t; i < B; i += 256) h[i] = 0;
    __syncthreads();
    int base = blockIdx.x * H_EPB;
    #pragma unroll
    for (int k = 0; k < H_EPT; ++k) {
        int e = base + k * 256 + t;
        if (e < E) atomicAdd(&h[dst[e] >> BSHIFT], 1);
    }
    __syncthreads();
    for (int i = t; i < B; i += 256) if (h[i]) atomicAdd(&bcnt[i], h[i]);
}

__global__ void __launch_bounds__(1024)
bucket_scan(const int* __restrict__ bcnt, int* __restrict__ boff,
            int* __restrict__ cursor, int B, int E) {
    __shared__ int sh[1024];
    int t = threadIdx.x;
    int v = (t < B) ? bcnt[t] : 0;
    sh[t] = v;
    __syncthreads();
    for (int d = 1; d < 1024; d <<= 1) {
        int u = (t >= d) ? sh[t - d] : 0;
        __syncthreads();
        sh[t] += u;
        __syncthreads();
    }
    if (t < B) { int ex = sh[t] - v; boff[t] = ex; cursor[t] = ex; }
    if (t == 0) boff[B] = E;
}

// Chunked scatter: each block reserves one contiguous run per touched bucket
// so record writes are line-local instead of fully random.
__global__ void __launch_bounds__(256)
bucket_scatter(const int* __restrict__ src, const int* __restrict__ dst,
               const float* __restrict__ w, int* __restrict__ cursor,
               int2* __restrict__ rec, int E, int B) {
    __shared__ int h[BMAX];
    __shared__ int cbase[BMAX];
    int t = threadIdx.x;
    for (int i = t; i < B; i += 256) h[i] = 0;
    __syncthreads();
    int blk = blockIdx.x * SC_EPB;
    int bkt[SC_EPT]; int rnk[SC_EPT]; int pv[SC_EPT]; float wv[SC_EPT];
    #pragma unroll
    for (int k = 0; k < SC_EPT; ++k) {
        int e = blk + k * 256 + t;
        if (e < E) {
            int d = dst[e];
            int bb = d >> BSHIFT;
            bkt[k] = bb;
            pv[k] = src[e] | ((d & (BNODES - 1)) << 17);  // src < 2^17 guarded at host
            wv[k] = w[e];
            rnk[k] = atomicAdd(&h[bb], 1);
        } else bkt[k] = -1;
    }
    __syncthreads();
    for (int i = t; i < B; i += 256)
        if (h[i]) cbase[i] = atomicAdd(&cursor[i], h[i]);
    __syncthreads();
    #pragma unroll
    for (int k = 0; k < SC_EPT; ++k) {
        if (bkt[k] >= 0) {
            int2 r; r.x = pv[k]; r.y = __float_as_int(wv[k]);
            rec[cbase[bkt[k]] + rnk[k]] = r;
        }
    }
}

// One block per bucket: accumulate into LDS, write out coalesced.
__global__ void __launch_bounds__(256)
bucket_accum(const float* __restrict__ x, const int2* __restrict__ rec,
             const int* __restrict__ boff, float* __restrict__ out, int N) {
    __shared__ float acc[BNODES * STRIDE];   // 33280 B
    int b = blockIdx.x;
    for (int i = threadIdx.x; i < BNODES * STRIDE; i += 256) acc[i] = 0.f;
    __syncthreads();
    int beg = boff[b], end = boff[b + 1];
    int g = threadIdx.x >> 4;   // 16 groups of 16 lanes
    int q = threadIdx.x & 15;
    for (int i0 = beg + g * 4; i0 < end; i0 += 64) {
        int nv = end - i0; if (nv > 4) nv = 4;
        int2 r[4];
        #pragma unroll
        for (int k = 0; k < 4; ++k) if (k < nv) r[k] = rec[i0 + k];
        #pragma unroll
        for (int k = 0; k < 4; ++k) {
            if (k < nv) {
                int v = r[k].x;
                int s = v & 0x1FFFF;
                int dl = v >> 17;
                float wv = __int_as_float(r[k].y);
                float4 xv = reinterpret_cast<const float4*>(x + (size_t)s * FDIM)[q];
                float* a = &acc[dl * STRIDE + q * 4];
                atomicAdd(a + 0, wv * xv.x);
                atomicAdd(a + 1, wv * xv.y);
                atomicAdd(a + 2, wv * xv.z);
                atomicAdd(a + 3, wv * xv.w);
            }
        }
    }
    __syncthreads();
    int nodeBase = b << BSHIFT;
    int nNodes = N - nodeBase; if (nNodes > BNODES) nNodes = BNODES;
    for (int i = threadIdx.x; i < (nNodes << 4); i += 256) {
        int ln = i >> 4, qq = i & 15;
        const float* a = &acc[ln * STRIDE + qq * 4];
        float4 vv = { a[0], a[1], a[2], a[3] };
        reinterpret_cast<float4*>(out + ((size_t)(nodeBase + ln) << 6))[qq] = vv;
    }
}

extern "C" void kernel_launch(void* const* d_in, const int* in_sizes, int n_in,
                              void* d_out, int out_size, void* d_ws, size_t ws_size,
                              hipStream_t stream) {
    const float* x  = (const float*)d_in[0];
    const float* w  = (const float*)d_in[1];
    const int* eidx = (const int*)d_in[2];
    int E = in_sizes[1];
    int N = out_size / FDIM;
    const int* src = eidx;
    const int* dst = eidx + E;
    float* out = (float*)d_out;

    int B = (N + BNODES - 1) >> BSHIFT;

    // workspace layout
    int* bcnt   = (int*)d_ws;            // B
    int* boff   = bcnt + B;              // B+1
    int* cursor = boff + B + 1;          // B
    size_t rec_off = (((size_t)(3 * B + 1)) * sizeof(int) + 7) & ~(size_t)7;
    int2* rec = (int2*)((char*)d_ws + rec_off);
    size_t need = rec_off + (size_t)E * sizeof(int2);

    if (ws_size < need || B > BMAX || N > (1 << 17)) {
        // fallback: atomic scatter
        hipMemsetAsync(out, 0, (size_t)out_size * sizeof(float), stream);
        int grid = (E * 16 + 255) / 256;
        scatter_edges_kernel<<<grid, 256, 0, stream>>>(x, w, src, dst, out, E);
        return;
    }

    hipMemsetAsync(bcnt, 0, (size_t)B * sizeof(int), stream);

    int gridH = (E + H_EPB - 1) / H_EPB;
    bucket_hist<<<gridH, 256, 0, stream>>>(dst, bcnt, E, B);
    bucket_scan<<<1, 1024, 0, stream>>>(bcnt, boff, cursor, B, E);
    int gridS = (E + SC_EPB - 1) / SC_EPB;
    bucket_scatter<<<gridS, 256, 0, stream>>>(src, dst, w, cursor, rec, E, B);
    bucket_accum<<<B, 256, 0, stream>>>(x, rec, boff, out, N);
}

// Round 5
// 172.637 us; speedup vs baseline: 3.1344x; 3.1344x over previous
//
#include <hip/hip_runtime.h>

// MessagePassing: out[dst[e], :] += w[e] * x[src[e], :]
// N=100000, E=1000000, F=64, fp32.
// Pipeline: bucket (128 nodes) hist -> scan -> chunked line-local scatter of
// packed (dl,src,w) records -> per-bucket block does in-LDS counting sort by
// local node, then register-only segment reduction, coalesced row writes.
// No global fp32 atomics, no hot-loop LDS atomics (1 LDS atomic per record).

#define FDIM 64
#define BSHIFT 7
#define BNODES 128          // nodes per bucket
#define BMAX 1024           // max buckets (N <= 131072 also needed for packing)
#define SC_EPT 16           // scatter: edges per thread
#define SC_EPB (256 * SC_EPT)
#define H_EPT 8             // hist: edges per thread
#define H_EPB (256 * H_EPT)
#define CAP 2048            // records per accum chunk
#define KPT (CAP / 256)     // 8 records per thread per chunk

// ---------------- fallback: atomic kernel ----------
__global__ void __launch_bounds__(256)
scatter_edges_kernel(const float* __restrict__ x,
                     const float* __restrict__ w,
                     const int* __restrict__ src,
                     const int* __restrict__ dst,
                     float* __restrict__ out,
                     int E) {
    int gid = blockIdx.x * blockDim.x + threadIdx.x;
    int e = gid >> 4;
    int q = gid & 15;
    if (e >= E) return;
    int s = src[e];
    int d = dst[e];
    float we = w[e];
    const float4* xrow = reinterpret_cast<const float4*>(x + (size_t)s * FDIM);
    float4 v = xrow[q];
    float* o = out + (size_t)d * FDIM + q * 4;
    atomicAdd(o + 0, we * v.x);
    atomicAdd(o + 1, we * v.y);
    atomicAdd(o + 2, we * v.z);
    atomicAdd(o + 3, we * v.w);
}

// ---------------- bucket path ----------------
__global__ void __launch_bounds__(256)
bucket_hist(const int* __restrict__ dst, int* __restrict__ bcnt, int E, int B) {
    __shared__ int h[BMAX];
    int t = threadIdx.x;
    for (int i = t; i < B; i += 256) h[i] = 0;
    __syncthreads();
    int base = blockIdx.x * H_EPB;
    #pragma unroll
    for (int k = 0; k < H_EPT; ++k) {
        int e = base + k * 256 + t;
        if (e < E) atomicAdd(&h[dst[e] >> BSHIFT], 1);
    }
    __syncthreads();
    for (int i = t; i < B; i += 256) if (h[i]) atomicAdd(&bcnt[i], h[i]);
}

__global__ void __launch_bounds__(1024)
bucket_scan(const int* __restrict__ bcnt, int* __restrict__ boff,
            int* __restrict__ cursor, int B, int E) {
    __shared__ int sh[1024];
    int t = threadIdx.x;
    int v = (t < B) ? bcnt[t] : 0;
    sh[t] = v;
    __syncthreads();
    for (int d = 1; d < 1024; d <<= 1) {
        int u = (t >= d) ? sh[t - d] : 0;
        __syncthreads();
        sh[t] += u;
        __syncthreads();
    }
    if (t < B) { int ex = sh[t] - v; boff[t] = ex; cursor[t] = ex; }
    if (t == 0) boff[B] = E;
}

// Chunked scatter: each block reserves one contiguous run per touched bucket.
__global__ void __launch_bounds__(256)
bucket_scatter(const int* __restrict__ src, const int* __restrict__ dst,
               const float* __restrict__ w, int* __restrict__ cursor,
               int2* __restrict__ rec, int E, int B) {
    __shared__ int h[BMAX];
    __shared__ int cbase[BMAX];
    int t = threadIdx.x;
    for (int i = t; i < B; i += 256) h[i] = 0;
    __syncthreads();
    int blk = blockIdx.x * SC_EPB;
    int bkt[SC_EPT]; int rnk[SC_EPT]; int pv[SC_EPT]; float wv[SC_EPT];
    #pragma unroll
    for (int k = 0; k < SC_EPT; ++k) {
        int e = blk + k * 256 + t;
        if (e < E) {
            int d = dst[e];
            int bb = d >> BSHIFT;
            bkt[k] = bb;
            pv[k] = src[e] | ((d & (BNODES - 1)) << 17);  // src < 2^17
            wv[k] = w[e];
            rnk[k] = atomicAdd(&h[bb], 1);
        } else bkt[k] = -1;
    }
    __syncthreads();
    for (int i = t; i < B; i += 256)
        if (h[i]) cbase[i] = atomicAdd(&cursor[i], h[i]);
    __syncthreads();
    #pragma unroll
    for (int k = 0; k < SC_EPT; ++k) {
        if (bkt[k] >= 0) {
            int2 r; r.x = pv[k]; r.y = __float_as_int(wv[k]);
            rec[cbase[bkt[k]] + rnk[k]] = r;
        }
    }
}

// One block per bucket: counting-sort records by local node in LDS, then
// register-only segment reduce; one coalesced float4 write per node chunk.
__global__ void __launch_bounds__(256)
bucket_sort_accum(const float* __restrict__ x, const int2* __restrict__ rec,
                  const int* __restrict__ boff, float* __restrict__ out, int N) {
    __shared__ int2 lrec[CAP];            // 16 KB
    __shared__ int nhist[BNODES];
    __shared__ int sscan[BNODES];
    __shared__ int noff[BNODES];
    int b = blockIdx.x;
    int t = threadIdx.x;
    int g = t >> 4;        // group 0..15
    int q = t & 15;        // lane-in-group -> float4 chunk of the row
    int beg = boff[b], end = boff[b + 1];

    float4 acc[8];         // group g owns nodes j*16+g, j=0..7
    #pragma unroll
    for (int j = 0; j < 8; ++j) acc[j] = make_float4(0.f, 0.f, 0.f, 0.f);

    for (int pos = beg; pos < end; pos += CAP) {
        int cnt = end - pos; if (cnt > CAP) cnt = CAP;
        // zero histogram
        if (t < BNODES) nhist[t] = 0;
        __syncthreads();
        // load my records, rank them
        int2 myrec[KPT]; int myrank[KPT]; int mybin[KPT];
        #pragma unroll
        for (int k = 0; k < KPT; ++k) {
            int i = k * 256 + t;
            if (i < cnt) {
                int2 r = rec[pos + i];
                int bin = r.x >> 17;
                myrec[k] = r;
                mybin[k] = bin;
                myrank[k] = atomicAdd(&nhist[bin], 1);
            } else mybin[k] = -1;
        }
        __syncthreads();
        // exclusive scan of 128 bins
        int v = (t < BNODES) ? nhist[t] : 0;
        if (t < BNODES) sscan[t] = v;
        __syncthreads();
        #pragma unroll
        for (int d = 1; d < BNODES; d <<= 1) {
            int u = (t >= d && t < BNODES) ? sscan[t - d] : 0;
            __syncthreads();
            if (t < BNODES) sscan[t] += u;
            __syncthreads();
        }
        if (t < BNODES) noff[t] = sscan[t] - v;
        __syncthreads();
        // scatter into sorted LDS buffer
        #pragma unroll
        for (int k = 0; k < KPT; ++k)
            if (mybin[k] >= 0) lrec[noff[mybin[k]] + myrank[k]] = myrec[k];
        __syncthreads();
        // register segment-reduce: group g walks nodes g, g+16, ...
        #pragma unroll
        for (int j = 0; j < 8; ++j) {
            int n = j * 16 + g;
            int sb = noff[n];
            int se = sb + nhist[n];
            for (int i = sb; i < se; ++i) {
                int2 r = lrec[i];          // 16 lanes same addr -> broadcast
                int s = r.x & 0x1FFFF;
                float wv = __int_as_float(r.y);
                float4 xv = reinterpret_cast<const float4*>(x + (size_t)s * FDIM)[q];
                acc[j].x += wv * xv.x;
                acc[j].y += wv * xv.y;
                acc[j].z += wv * xv.z;
                acc[j].w += wv * xv.w;
            }
        }
        __syncthreads();   // before LDS reuse in next chunk
    }

    // write out: node rows are fully owned by this block
    int nodeBase = b << BSHIFT;
    #pragma unroll
    for (int j = 0; j < 8; ++j) {
        int row = nodeBase + j * 16 + g;
        if (row < N)
            reinterpret_cast<float4*>(out + ((size_t)row << 6))[q] = acc[j];
    }
}

extern "C" void kernel_launch(void* const* d_in, const int* in_sizes, int n_in,
                              void* d_out, int out_size, void* d_ws, size_t ws_size,
                              hipStream_t stream) {
    const float* x  = (const float*)d_in[0];
    const float* w  = (const float*)d_in[1];
    const int* eidx = (const int*)d_in[2];
    int E = in_sizes[1];
    int N = out_size / FDIM;
    const int* src = eidx;
    const int* dst = eidx + E;
    float* out = (float*)d_out;

    int B = (N + BNODES - 1) >> BSHIFT;

    // workspace layout
    int* bcnt   = (int*)d_ws;            // B
    int* boff   = bcnt + B;              // B+1
    int* cursor = boff + B + 1;          // B
    size_t rec_off = (((size_t)(3 * B + 1)) * sizeof(int) + 7) & ~(size_t)7;
    int2* rec = (int2*)((char*)d_ws + rec_off);
    size_t need = rec_off + (size_t)E * sizeof(int2);

    if (ws_size < need || B > BMAX || N > (1 << 17)) {
        hipMemsetAsync(out, 0, (size_t)out_size * sizeof(float), stream);
        int grid = (E * 16 + 255) / 256;
        scatter_edges_kernel<<<grid, 256, 0, stream>>>(x, w, src, dst, out, E);
        return;
    }

    hipMemsetAsync(bcnt, 0, (size_t)B * sizeof(int), stream);

    int gridH = (E + H_EPB - 1) / H_EPB;
    bucket_hist<<<gridH, 256, 0, stream>>>(dst, bcnt, E, B);
    bucket_scan<<<1, 1024, 0, stream>>>(bcnt, boff, cursor, B, E);
    int gridS = (E + SC_EPB - 1) / SC_EPB;
    bucket_scatter<<<gridS, 256, 0, stream>>>(src, dst, w, cursor, rec, E, B);
    bucket_sort_accum<<<B, 256, 0, stream>>>(x, rec, boff, out, N);
}